// Round 2
// baseline (234.657 us; speedup 1.0000x reference)
//
#include <hip/hip_runtime.h>

#define HID 128
#define C2  256
#define NODES 2032
#define NPT 127
#define NTREES 16

typedef short bf16x8 __attribute__((ext_vector_type(8)));
typedef short bf16x4 __attribute__((ext_vector_type(4)));
typedef float f32x4  __attribute__((ext_vector_type(4)));

__device__ __forceinline__ float bf2f(short s) {
  union { unsigned u; float f; } c; c.u = ((unsigned)(unsigned short)s) << 16; return c.f;
}
__device__ __forceinline__ unsigned short f2bf(float f) {
  union { float f; unsigned u; } c; c.f = f;
  unsigned u = c.u;
  return (unsigned short)((u + 0x7fffu + ((u >> 16) & 1u)) >> 16);
}
// post-order index (within one 127-node tree) of the p-th node at a level
// whose subtree size is sst = 2^(L+1)-1
__device__ __forceinline__ int tree_idx(int p, int sst) {
  return (p + 1) * sst + p - __popc(p) - 1;
}

// V fp32 -> hi/lo bf16 planes
__global__ void vconv_kernel(const float* __restrict__ V, short* __restrict__ Vhi,
                             short* __restrict__ Vlo, int n4) {
  int i = blockIdx.x * blockDim.x + threadIdx.x;
  if (i >= n4) return;
  const float4 v = ((const float4*)V)[i];
  bf16x4 oh, ol;
  float x;
  x = v.x; oh[0] = (short)f2bf(x); ol[0] = (short)f2bf(x - bf2f(oh[0]));
  x = v.y; oh[1] = (short)f2bf(x); ol[1] = (short)f2bf(x - bf2f(oh[1]));
  x = v.z; oh[2] = (short)f2bf(x); ol[2] = (short)f2bf(x - bf2f(oh[2]));
  x = v.w; oh[3] = (short)f2bf(x); ol[3] = (short)f2bf(x - bf2f(oh[3]));
  ((bf16x4*)Vhi)[i] = oh;
  ((bf16x4*)Vlo)[i] = ol;
}

__global__ void leaf_kernel(const float* __restrict__ embed, const int* __restrict__ word_idx,
                            float* __restrict__ Hf, short* __restrict__ Hhi,
                            short* __restrict__ Hlo) {
  int leaf = blockIdx.x;                  // 0..1023
  int tree = leaf >> 6, p = leaf & 63;
  int g = tree * NPT + 2 * p - __popc(p); // leaf formula: L=0, sst=1
  int wi = word_idx[g];
  const float2 e = ((const float2*)(embed + (size_t)wi * HID))[threadIdx.x];
  ((float2*)(Hf + (size_t)g * HID))[threadIdx.x] = e;
  unsigned short h0 = f2bf(e.x), h1 = f2bf(e.y);
  unsigned short l0 = f2bf(e.x - bf2f(h0)), l1 = f2bf(e.y - bf2f(h1));
  ((unsigned*)(Hhi + (size_t)g * HID))[threadIdx.x] = (unsigned)h0 | ((unsigned)h1 << 16);
  ((unsigned*)(Hlo + (size_t)g * HID))[threadIdx.x] = (unsigned)l0 | ((unsigned)l1 << 16);
}

// One block = one h (blockIdx.x) x one tile of NF*16 nodes (blockIdx.y).
// 4 waves, wave w owns k-strip [64w, 64w+64). K-loop over l (256) with
// mfma_f32_16x16x32_bf16, 3 split passes: Vhi*chi + Vhi*clo + Vlo*chi.
// Epilogue contracts T with fp32 c, adds c@W + b (fp32), tanh, stores
// fp32 H + hi/lo bf16 planes.
template<int NF>
__global__ __launch_bounds__(256) void level_kernel(
    const short* __restrict__ Vhi, const short* __restrict__ Vlo,
    float* __restrict__ Hf, short* __restrict__ Hhi, short* __restrict__ Hlo,
    const float* __restrict__ W, const float* __restrict__ bb,
    const int* __restrict__ left, const int* __restrict__ right,
    int lognpt)
{
  const int h    = blockIdx.x;
  const int tid  = threadIdx.x;
  const int lane = tid & 63;
  const int w    = tid >> 6;
  const int lo16 = lane & 15;
  const int kq   = lane >> 4;
  const int n0   = blockIdx.y * (NF * 16);
  const int npt_mask = (1 << lognpt) - 1;
  const int sst  = (1 << (7 - lognpt)) - 1;

  int lg[NF], rg[NF];
#pragma unroll
  for (int cf = 0; cf < NF; ++cf) {
    int n = n0 + cf * 16 + lo16;
    int tree = n >> lognpt;
    int p = n & npt_mask;
    int g = tree * NPT + tree_idx(p, sst);
    lg[cf] = left[g];
    rg[cf] = right[g];
  }

  f32x4 acc[4][NF];
#pragma unroll
  for (int rf = 0; rf < 4; ++rf)
#pragma unroll
    for (int cf = 0; cf < NF; ++cf) {
      f32x4 z = {0.f, 0.f, 0.f, 0.f};
      acc[rf][cf] = z;
    }

  const short* __restrict__ Vhh = Vhi + (size_t)h * C2 * C2;
  const short* __restrict__ Vhl = Vlo + (size_t)h * C2 * C2;

#pragma unroll
  for (int l0 = 0; l0 < 256; l0 += 32) {
    const int loff = (l0 & 127) + kq * 8;
    bf16x8 Bh[NF], Bl[NF];
#pragma unroll
    for (int cf = 0; cf < NF; ++cf) {
      const int child = (l0 < 128) ? lg[cf] : rg[cf];
      Bh[cf] = *(const bf16x8*)(Hhi + (size_t)child * HID + loff);
      Bl[cf] = *(const bf16x8*)(Hlo + (size_t)child * HID + loff);
    }
#pragma unroll
    for (int rf = 0; rf < 4; ++rf) {
      const int k = w * 64 + rf * 16 + lo16;
      const bf16x8 Ah = *(const bf16x8*)(Vhh + (size_t)k * C2 + l0 + kq * 8);
      const bf16x8 Al = *(const bf16x8*)(Vhl + (size_t)k * C2 + l0 + kq * 8);
#pragma unroll
      for (int cf = 0; cf < NF; ++cf) {
        acc[rf][cf] = __builtin_amdgcn_mfma_f32_16x16x32_bf16(Ah, Bh[cf], acc[rf][cf], 0, 0, 0);
        acc[rf][cf] = __builtin_amdgcn_mfma_f32_16x16x32_bf16(Ah, Bl[cf], acc[rf][cf], 0, 0, 0);
        acc[rf][cf] = __builtin_amdgcn_mfma_f32_16x16x32_bf16(Al, Bh[cf], acc[rf][cf], 0, 0, 0);
      }
    }
  }

  // step-2 contraction: xVx_partial[n] = sum_{k in this wave's strip} c_n[k]*T[k,n]
  // c read in fp32 (exact).
  float part[NF];
#pragma unroll
  for (int cf = 0; cf < NF; ++cf) part[cf] = 0.f;
#pragma unroll
  for (int rf = 0; rf < 4; ++rf) {
    const int kb = w * 64 + rf * 16 + kq * 4;   // 4 consecutive k per lane (D rows)
    const int ko = kb & 127;
    const bool hi = kb >= 128;
#pragma unroll
    for (int cf = 0; cf < NF; ++cf) {
      const int child = hi ? rg[cf] : lg[cf];
      const f32x4 cv = *(const f32x4*)(Hf + (size_t)child * HID + ko);
      part[cf] += cv[0] * acc[rf][cf][0] + cv[1] * acc[rf][cf][1]
                + cv[2] * acc[rf][cf][2] + cv[3] * acc[rf][cf][3];
    }
  }
#pragma unroll
  for (int cf = 0; cf < NF; ++cf) {
    part[cf] += __shfl_xor(part[cf], 16);
    part[cf] += __shfl_xor(part[cf], 32);
  }

  __shared__ float redA[4][64];
  __shared__ float redB[4][64];
  if (kq == 0) {
#pragma unroll
    for (int cf = 0; cf < NF; ++cf) redA[w][cf * 16 + lo16] = part[cf];
  }

  // W-term: wave w covers l in [64w, 64w+64); lane owns node n0+lane. fp32 c.
  const bool valid = lane < NF * 16;
  {
    int n = n0 + (valid ? lane : 0);
    int tree = n >> lognpt;
    int p = n & npt_mask;
    int g = tree * NPT + tree_idx(p, sst);
    int child = (w < 2) ? left[g] : right[g];
    const float* crow = Hf + (size_t)child * HID + (w & 1) * 64;
    const int wl0 = w * 64;
    float cw = 0.f;
#pragma unroll
    for (int j = 0; j < 16; ++j) {
      float4 cv4 = ((const float4*)crow)[j];
      const float* wr = W + (size_t)(wl0 + j * 4) * HID + h;
      cw += cv4.x * wr[0] + cv4.y * wr[HID] + cv4.z * wr[2 * HID] + cv4.w * wr[3 * HID];
    }
    redB[w][lane] = valid ? cw : 0.f;
  }
  __syncthreads();

  if (w == 0 && valid) {
    float v = redA[0][lane] + redA[1][lane] + redA[2][lane] + redA[3][lane]
            + redB[0][lane] + redB[1][lane] + redB[2][lane] + redB[3][lane]
            + bb[h];
    float t = tanhf(v);
    int n = n0 + lane;
    int tree = n >> lognpt;
    int p = n & npt_mask;
    int g = tree * NPT + tree_idx(p, sst);
    Hf[(size_t)g * HID + h] = t;
    unsigned short th = f2bf(t);
    ((unsigned short*)Hhi)[(size_t)g * HID + h] = th;
    ((unsigned short*)Hlo)[(size_t)g * HID + h] = f2bf(t - bf2f(th));
  }
}

__global__ void out_kernel(const float* __restrict__ Hf, const float* __restrict__ Wout,
                           const float* __restrict__ Wb, float* __restrict__ out) {
  int n = blockIdx.x * blockDim.x + threadIdx.x;
  if (n >= NODES) return;
  const float* hrow = Hf + (size_t)n * HID;
  float lg0 = Wb[0], lg1 = Wb[1], lg2 = Wb[2], lg3 = Wb[3], lg4 = Wb[4];
#pragma unroll
  for (int j = 0; j < 32; ++j) {
    float4 hv = ((const float4*)hrow)[j];
    const float* wr = Wout + (size_t)(j * 4) * 5;
    lg0 += hv.x * wr[0] + hv.y * wr[5] + hv.z * wr[10] + hv.w * wr[15];
    lg1 += hv.x * wr[1] + hv.y * wr[6] + hv.z * wr[11] + hv.w * wr[16];
    lg2 += hv.x * wr[2] + hv.y * wr[7] + hv.z * wr[12] + hv.w * wr[17];
    lg3 += hv.x * wr[3] + hv.y * wr[8] + hv.z * wr[13] + hv.w * wr[18];
    lg4 += hv.x * wr[4] + hv.y * wr[9] + hv.z * wr[14] + hv.w * wr[19];
  }
  float m = fmaxf(fmaxf(fmaxf(lg0, lg1), fmaxf(lg2, lg3)), lg4);
  float ss = expf(lg0 - m) + expf(lg1 - m) + expf(lg2 - m) + expf(lg3 - m) + expf(lg4 - m);
  float lse = m + logf(ss);
  float* o = out + (size_t)n * 5;
  o[0] = lg0 - lse; o[1] = lg1 - lse; o[2] = lg2 - lse; o[3] = lg3 - lse; o[4] = lg4 - lse;
}

extern "C" void kernel_launch(void* const* d_in, const int* in_sizes, int n_in,
                              void* d_out, int out_size, void* d_ws, size_t ws_size,
                              hipStream_t stream) {
  const float* embed = (const float*)d_in[0];
  const float* V     = (const float*)d_in[1];
  const float* W     = (const float*)d_in[2];
  const float* b     = (const float*)d_in[3];
  const float* Wout  = (const float*)d_in[4];
  const float* Woutb = (const float*)d_in[5];
  // d_in[6] = is_leaf (unused; leaf-ness is structural)
  const int* word_idx = (const int*)d_in[7];
  const int* left     = (const int*)d_in[8];
  const int* right    = (const int*)d_in[9];
  float* out = (float*)d_out;

  float* Hf  = (float*)d_ws;                        // [2032][128] fp32
  short* Hhi = (short*)(Hf + (size_t)NODES * HID);  // [2032][128] bf16
  short* Hlo = Hhi + (size_t)NODES * HID;           // [2032][128] bf16
  short* Vhi = Hlo + (size_t)NODES * HID;           // [128][256][256] bf16
  short* Vlo = Vhi + (size_t)HID * C2 * C2;         // [128][256][256] bf16

  const int n4 = (HID * C2 * C2) / 4;
  vconv_kernel<<<(n4 + 255) / 256, 256, 0, stream>>>(V, Vhi, Vlo, n4);
  leaf_kernel<<<1024, 64, 0, stream>>>(embed, word_idx, Hf, Hhi, Hlo);

  // levels L=1..6: npt = 64>>L nodes/tree, m = 16*npt total, lognpt = 6-L
  level_kernel<4><<<dim3(128, 8), 256, 0, stream>>>(Vhi, Vlo, Hf, Hhi, Hlo, W, b, left, right, 5); // m=512
  level_kernel<4><<<dim3(128, 4), 256, 0, stream>>>(Vhi, Vlo, Hf, Hhi, Hlo, W, b, left, right, 4); // m=256
  level_kernel<4><<<dim3(128, 2), 256, 0, stream>>>(Vhi, Vlo, Hf, Hhi, Hlo, W, b, left, right, 3); // m=128
  level_kernel<4><<<dim3(128, 1), 256, 0, stream>>>(Vhi, Vlo, Hf, Hhi, Hlo, W, b, left, right, 2); // m=64
  level_kernel<2><<<dim3(128, 1), 256, 0, stream>>>(Vhi, Vlo, Hf, Hhi, Hlo, W, b, left, right, 1); // m=32
  level_kernel<1><<<dim3(128, 1), 256, 0, stream>>>(Vhi, Vlo, Hf, Hhi, Hlo, W, b, left, right, 0); // m=16

  out_kernel<<<(NODES + 255) / 256, 256, 0, stream>>>(Hf, Wout, Woutb, out);
}

// Round 4
// 232.705 us; speedup vs baseline: 1.0084x; 1.0084x over previous
//
#include <hip/hip_runtime.h>

#define HID 128
#define C2  256
#define NODES 2032
#define NPT 127
#define NTREES 16

typedef short bf16x8 __attribute__((ext_vector_type(8)));
typedef short bf16x4 __attribute__((ext_vector_type(4)));
typedef float f32x4  __attribute__((ext_vector_type(4)));

__device__ __forceinline__ float bf2f(short s) {
  union { unsigned u; float f; } c; c.u = ((unsigned)(unsigned short)s) << 16; return c.f;
}
__device__ __forceinline__ unsigned short f2bf(float f) {
  union { float f; unsigned u; } c; c.f = f;
  unsigned u = c.u;
  return (unsigned short)((u + 0x7fffu + ((u >> 16) & 1u)) >> 16);
}
// post-order index (within one 127-node tree) of the p-th node at a level
// whose subtree size is sst = 2^(L+1)-1
__device__ __forceinline__ int tree_idx(int p, int sst) {
  return (p + 1) * sst + p - __popc(p) - 1;
}
// XCD-pinned h mapping: XCD = bid%8 owns h in [16*XCD, 16*XCD+16)
__device__ __forceinline__ int bid_to_h(int bid) {
  return (bid & 7) * 16 + ((bid >> 3) & 15);
}

// V fp32 -> hi/lo bf16 planes. 1024 blocks, XCD-pinned to match the readers:
// block bid writes chunk (bid>>7) of h-slice bid_to_h(bid).
__global__ void vconv_kernel(const float* __restrict__ V, short* __restrict__ Vhi,
                             short* __restrict__ Vlo) {
  const int bid = blockIdx.x;
  const int h = bid_to_h(bid);
  const int chunk = bid >> 7;                  // 0..7
  // h-slice = 65536 floats = 16384 float4; chunk = 2048 float4; thread: 8 f4
  const size_t base = (size_t)h * 16384 + (size_t)chunk * 2048 + threadIdx.x;
#pragma unroll
  for (int j = 0; j < 8; ++j) {
    const size_t i = base + j * 256;
    const float4 v = ((const float4*)V)[i];
    bf16x4 oh, ol;
    float x;
    x = v.x; oh[0] = (short)f2bf(x); ol[0] = (short)f2bf(x - bf2f(oh[0]));
    x = v.y; oh[1] = (short)f2bf(x); ol[1] = (short)f2bf(x - bf2f(oh[1]));
    x = v.z; oh[2] = (short)f2bf(x); ol[2] = (short)f2bf(x - bf2f(oh[2]));
    x = v.w; oh[3] = (short)f2bf(x); ol[3] = (short)f2bf(x - bf2f(oh[3]));
    ((bf16x4*)Vhi)[i] = oh;
    ((bf16x4*)Vlo)[i] = ol;
  }
}

__global__ void leaf_kernel(const float* __restrict__ embed, const int* __restrict__ word_idx,
                            float* __restrict__ Hf, short* __restrict__ Hhi,
                            short* __restrict__ Hlo) {
  int leaf = blockIdx.x;                  // 0..1023
  int tree = leaf >> 6, p = leaf & 63;
  int g = tree * NPT + 2 * p - __popc(p); // leaf formula: L=0, sst=1
  int wi = word_idx[g];
  const float2 e = ((const float2*)(embed + (size_t)wi * HID))[threadIdx.x];
  ((float2*)(Hf + (size_t)g * HID))[threadIdx.x] = e;
  unsigned short h0 = f2bf(e.x), h1 = f2bf(e.y);
  unsigned short l0 = f2bf(e.x - bf2f(h0)), l1 = f2bf(e.y - bf2f(h1));
  ((unsigned*)(Hhi + (size_t)g * HID))[threadIdx.x] = (unsigned)h0 | ((unsigned)h1 << 16);
  ((unsigned*)(Hlo + (size_t)g * HID))[threadIdx.x] = (unsigned)l0 | ((unsigned)l1 << 16);
}

// One block = one h x one tile of NF*16 nodes; 1-D grid, XCD-pinned:
// h = bid_to_h(bid), tile = bid>>7. 4 waves, wave w owns k-strip [64w, 64w+64).
// K-loop over l (256) with mfma_f32_16x16x32_bf16, 3 split passes:
// Vhi*chi + Vhi*clo + Vlo*chi. Epilogue contracts T with fp32 c, adds
// c@W + b (fp32), tanh, stores fp32 H + hi/lo bf16 planes.
template<int NF>
__global__ __launch_bounds__(256) void level_kernel(
    const short* __restrict__ Vhi, const short* __restrict__ Vlo,
    float* __restrict__ Hf, short* __restrict__ Hhi, short* __restrict__ Hlo,
    const float* __restrict__ W, const float* __restrict__ bb,
    const int* __restrict__ left, const int* __restrict__ right,
    int lognpt)
{
  const int bid  = blockIdx.x;
  const int h    = bid_to_h(bid);
  const int tid  = threadIdx.x;
  const int lane = tid & 63;
  const int w    = tid >> 6;
  const int lo16 = lane & 15;
  const int kq   = lane >> 4;
  const int n0   = (bid >> 7) * (NF * 16);
  const int npt_mask = (1 << lognpt) - 1;
  const int sst  = (1 << (7 - lognpt)) - 1;

  int lg[NF], rg[NF];
#pragma unroll
  for (int cf = 0; cf < NF; ++cf) {
    int n = n0 + cf * 16 + lo16;
    int tree = n >> lognpt;
    int p = n & npt_mask;
    int g = tree * NPT + tree_idx(p, sst);
    lg[cf] = left[g];
    rg[cf] = right[g];
  }

  f32x4 acc[4][NF];
#pragma unroll
  for (int rf = 0; rf < 4; ++rf)
#pragma unroll
    for (int cf = 0; cf < NF; ++cf) {
      f32x4 z = {0.f, 0.f, 0.f, 0.f};
      acc[rf][cf] = z;
    }

  const short* __restrict__ Vhh = Vhi + (size_t)h * C2 * C2;
  const short* __restrict__ Vhl = Vlo + (size_t)h * C2 * C2;

#pragma unroll
  for (int l0 = 0; l0 < 256; l0 += 32) {
    const int loff = (l0 & 127) + kq * 8;
    bf16x8 Bh[NF], Bl[NF];
#pragma unroll
    for (int cf = 0; cf < NF; ++cf) {
      const int child = (l0 < 128) ? lg[cf] : rg[cf];
      Bh[cf] = *(const bf16x8*)(Hhi + (size_t)child * HID + loff);
      Bl[cf] = *(const bf16x8*)(Hlo + (size_t)child * HID + loff);
    }
#pragma unroll
    for (int rf = 0; rf < 4; ++rf) {
      const int k = w * 64 + rf * 16 + lo16;
      const bf16x8 Ah = *(const bf16x8*)(Vhh + (size_t)k * C2 + l0 + kq * 8);
      const bf16x8 Al = *(const bf16x8*)(Vhl + (size_t)k * C2 + l0 + kq * 8);
#pragma unroll
      for (int cf = 0; cf < NF; ++cf) {
        acc[rf][cf] = __builtin_amdgcn_mfma_f32_16x16x32_bf16(Ah, Bh[cf], acc[rf][cf], 0, 0, 0);
        acc[rf][cf] = __builtin_amdgcn_mfma_f32_16x16x32_bf16(Ah, Bl[cf], acc[rf][cf], 0, 0, 0);
        acc[rf][cf] = __builtin_amdgcn_mfma_f32_16x16x32_bf16(Al, Bh[cf], acc[rf][cf], 0, 0, 0);
      }
    }
  }

  // step-2 contraction: xVx_partial[n] = sum_{k in this wave's strip} c_n[k]*T[k,n]
  // c read in fp32 (exact).
  float part[NF];
#pragma unroll
  for (int cf = 0; cf < NF; ++cf) part[cf] = 0.f;
#pragma unroll
  for (int rf = 0; rf < 4; ++rf) {
    const int kb = w * 64 + rf * 16 + kq * 4;   // 4 consecutive k per lane (D rows)
    const int ko = kb & 127;
    const bool hi = kb >= 128;
#pragma unroll
    for (int cf = 0; cf < NF; ++cf) {
      const int child = hi ? rg[cf] : lg[cf];
      const f32x4 cv = *(const f32x4*)(Hf + (size_t)child * HID + ko);
      part[cf] += cv[0] * acc[rf][cf][0] + cv[1] * acc[rf][cf][1]
                + cv[2] * acc[rf][cf][2] + cv[3] * acc[rf][cf][3];
    }
  }
#pragma unroll
  for (int cf = 0; cf < NF; ++cf) {
    part[cf] += __shfl_xor(part[cf], 16);
    part[cf] += __shfl_xor(part[cf], 32);
  }

  __shared__ float redA[4][64];
  __shared__ float redB[4][64];
  if (kq == 0) {
#pragma unroll
    for (int cf = 0; cf < NF; ++cf) redA[w][cf * 16 + lo16] = part[cf];
  }

  // W-term: wave w covers l in [64w, 64w+64); lane owns node n0+lane. fp32 c.
  const bool valid = lane < NF * 16;
  {
    int n = n0 + (valid ? lane : 0);
    int tree = n >> lognpt;
    int p = n & npt_mask;
    int g = tree * NPT + tree_idx(p, sst);
    int child = (w < 2) ? left[g] : right[g];
    const float* crow = Hf + (size_t)child * HID + (w & 1) * 64;
    const int wl0 = w * 64;
    float cw = 0.f;
#pragma unroll
    for (int j = 0; j < 16; ++j) {
      float4 cv4 = ((const float4*)crow)[j];
      const float* wr = W + (size_t)(wl0 + j * 4) * HID + h;
      cw += cv4.x * wr[0] + cv4.y * wr[HID] + cv4.z * wr[2 * HID] + cv4.w * wr[3 * HID];
    }
    redB[w][lane] = valid ? cw : 0.f;
  }
  __syncthreads();

  if (w == 0 && valid) {
    float v = redA[0][lane] + redA[1][lane] + redA[2][lane] + redA[3][lane]
            + redB[0][lane] + redB[1][lane] + redB[2][lane] + redB[3][lane]
            + bb[h];
    float t = tanhf(v);
    int n = n0 + lane;
    int tree = n >> lognpt;
    int p = n & npt_mask;
    int g = tree * NPT + tree_idx(p, sst);
    Hf[(size_t)g * HID + h] = t;
    unsigned short th = f2bf(t);
    ((unsigned short*)Hhi)[(size_t)g * HID + h] = th;
    ((unsigned short*)Hlo)[(size_t)g * HID + h] = f2bf(t - bf2f(th));
  }
}

__global__ void out_kernel(const float* __restrict__ Hf, const float* __restrict__ Wout,
                           const float* __restrict__ Wb, float* __restrict__ out) {
  int n = blockIdx.x * blockDim.x + threadIdx.x;
  if (n >= NODES) return;
  const float* hrow = Hf + (size_t)n * HID;
  float lg0 = Wb[0], lg1 = Wb[1], lg2 = Wb[2], lg3 = Wb[3], lg4 = Wb[4];
#pragma unroll
  for (int j = 0; j < 32; ++j) {
    float4 hv = ((const float4*)hrow)[j];
    const float* wr = Wout + (size_t)(j * 4) * 5;
    lg0 += hv.x * wr[0] + hv.y * wr[5] + hv.z * wr[10] + hv.w * wr[15];
    lg1 += hv.x * wr[1] + hv.y * wr[6] + hv.z * wr[11] + hv.w * wr[16];
    lg2 += hv.x * wr[2] + hv.y * wr[7] + hv.z * wr[12] + hv.w * wr[17];
    lg3 += hv.x * wr[3] + hv.y * wr[8] + hv.z * wr[13] + hv.w * wr[18];
    lg4 += hv.x * wr[4] + hv.y * wr[9] + hv.z * wr[14] + hv.w * wr[19];
  }
  float m = fmaxf(fmaxf(fmaxf(lg0, lg1), fmaxf(lg2, lg3)), lg4);
  float ss = expf(lg0 - m) + expf(lg1 - m) + expf(lg2 - m) + expf(lg3 - m) + expf(lg4 - m);
  float lse = m + logf(ss);
  float* o = out + (size_t)n * 5;
  o[0] = lg0 - lse; o[1] = lg1 - lse; o[2] = lg2 - lse; o[3] = lg3 - lse; o[4] = lg4 - lse;
}

extern "C" void kernel_launch(void* const* d_in, const int* in_sizes, int n_in,
                              void* d_out, int out_size, void* d_ws, size_t ws_size,
                              hipStream_t stream) {
  const float* embed = (const float*)d_in[0];
  const float* V     = (const float*)d_in[1];
  const float* W     = (const float*)d_in[2];
  const float* b     = (const float*)d_in[3];
  const float* Wout  = (const float*)d_in[4];
  const float* Woutb = (const float*)d_in[5];
  // d_in[6] = is_leaf (unused; leaf-ness is structural)
  const int* word_idx = (const int*)d_in[7];
  const int* left     = (const int*)d_in[8];
  const int* right    = (const int*)d_in[9];
  float* out = (float*)d_out;

  float* Hf  = (float*)d_ws;                        // [2032][128] fp32
  short* Hhi = (short*)(Hf + (size_t)NODES * HID);  // [2032][128] bf16
  short* Hlo = Hhi + (size_t)NODES * HID;           // [2032][128] bf16
  short* Vhi = Hlo + (size_t)NODES * HID;           // [128][256][256] bf16
  short* Vlo = Vhi + (size_t)HID * C2 * C2;         // [128][256][256] bf16

  vconv_kernel<<<1024, 256, 0, stream>>>(V, Vhi, Vlo);
  leaf_kernel<<<1024, 64, 0, stream>>>(embed, word_idx, Hf, Hhi, Hlo);

  // levels L=1..6: npt = 64>>L nodes/tree, m = 16*npt total, lognpt = 6-L
  // 1-D grids, XCD-pinned h mapping (h = (bid%8)*16 + (bid>>3)&15)
  level_kernel<4><<<1024, 256, 0, stream>>>(Vhi, Vlo, Hf, Hhi, Hlo, W, b, left, right, 5); // m=512
  level_kernel<4><<< 512, 256, 0, stream>>>(Vhi, Vlo, Hf, Hhi, Hlo, W, b, left, right, 4); // m=256
  level_kernel<4><<< 256, 256, 0, stream>>>(Vhi, Vlo, Hf, Hhi, Hlo, W, b, left, right, 3); // m=128
  level_kernel<4><<< 128, 256, 0, stream>>>(Vhi, Vlo, Hf, Hhi, Hlo, W, b, left, right, 2); // m=64
  level_kernel<2><<< 128, 256, 0, stream>>>(Vhi, Vlo, Hf, Hhi, Hlo, W, b, left, right, 1); // m=32
  level_kernel<1><<< 128, 256, 0, stream>>>(Vhi, Vlo, Hf, Hhi, Hlo, W, b, left, right, 0); // m=16

  out_kernel<<<(NODES + 255) / 256, 256, 0, stream>>>(Hf, Wout, Woutb, out);
}